// Round 8
// baseline (148.529 us; speedup 1.0000x reference)
//
#include <hip/hip_runtime.h>
#include <hip/hip_bf16.h>

#define NS     256
#define FEAT   8192
#define BD     128
#define CD     16
#define NOUT   2048
#define OUTW   8320              // FEAT + BD
#define KSPLIT 16
#define KC     (FEAT / KSPLIT)   // 512
#define BK     32
#define NSTEP  (KC / BK)         // 16
#define BM     128
#define BN     64
#define BBP    40                // Bbf pitch in shorts (80 B -> 2-way-free banks)
#define PASSES 6                 // DMA probe passes over T (measurement)

typedef float f32x4 __attribute__((ext_vector_type(4)));
typedef short bf16x8 __attribute__((ext_vector_type(8)));
typedef short bf16x4 __attribute__((ext_vector_type(4)));

typedef unsigned int u32;
typedef __attribute__((address_space(3))) u32 lds_u32;
typedef const __attribute__((address_space(1))) u32 gbl_u32;

__device__ __forceinline__ void gl_lds16(const void* g, void* l) {
    __builtin_amdgcn_global_load_lds((gbl_u32*)g, (lds_u32*)l, 16, 0, 0);
}

__device__ __forceinline__ bf16x4 cvt4(float a, float b, float c, float d) {
    union { __hip_bfloat162 h[2]; bf16x4 s; } u;
    u.h[0] = __float22bfloat162_rn(float2{a, b});
    u.h[1] = __float22bfloat162_rn(float2{c, d});
    return u.s;
}

__device__ __forceinline__ f32x4 bf4_to_f32(bf16x4 s) {
    f32x4 r;
    r.x = __uint_as_float(((u32)(unsigned short)s.x) << 16);
    r.y = __uint_as_float(((u32)(unsigned short)s.y) << 16);
    r.z = __uint_as_float(((u32)(unsigned short)s.z) << 16);
    r.w = __uint_as_float(((u32)(unsigned short)s.w) << 16);
    return r;
}

// -------------------------------- copy inp -> out, zero o-cols, produce Abf -
__global__ __launch_bounds__(256) void mbd_copy_kernel(const float* __restrict__ in,
                                                       float* __restrict__ out,
                                                       short* __restrict__ Abf) {
    int row = blockIdx.y;
    int c4  = blockIdx.x * 256 + threadIdx.x;
    if (c4 < 2048) {
        f32x4 v = *(const f32x4*)(in + (size_t)row * FEAT + c4 * 4);
        *(f32x4*)(out + (size_t)row * OUTW + c4 * 4) = v;
        *(bf16x4*)(Abf + (size_t)row * FEAT + c4 * 4) = cvt4(v.x, v.y, v.z, v.w);
    } else if (c4 < 2080) {
        *(f32x4*)(out + (size_t)row * OUTW + c4 * 4) = (f32x4){0.f, 0.f, 0.f, 0.f};
    }
}

// ---------------------------------------------------------------- GEMM ------
// Mt_part[kc][col][row] (bf16) = (Abf[:, kc-slice] @ T[kc-slice, :])^T.
// 256 threads (4 waves), BM=128 x BN=64, 58 KB LDS -> 2 blocks/CU: two
// INDEPENDENT barrier domains per CU so DMA-wait of one block overlaps the
// LDS/MFMA phases of the other (the R6/R7 1-block lockstep paid the SUM).
// Ring-3 slots, counted vmcnt(4) (4 gl_lds16 per wave per tile).
// A swizzle: storage quad = logical ^ ((row>>1)&3)  -> 2-way-free b128 reads.
__global__ __launch_bounds__(256, 2) void mbd_gemm_kernel(const short* __restrict__ Abf,
                                                          const float* __restrict__ T,
                                                          short* __restrict__ Mt) {
    __shared__ __align__(16) short Als[3][BM * BK];   // 3 x 8 KB
    __shared__ __align__(16) float Bfs[3][BK * BN];   // 3 x 8 KB
    __shared__ __align__(16) short Bbf[2][BN * BBP];  // 2 x 5 KB

    const int tid = threadIdx.x, lane = tid & 63, l15 = lane & 15, w = tid >> 6;
    const int wm = (w & 1) * 64, wn = (w >> 1) * 32;   // wave tile 64x32

    const int bx = blockIdx.x;
    const int kc = bx & 15;                 // bx%8 == kc%8 -> A slabs L2-resident/XCD
    const int rest = bx >> 4;
    const int m0 = (rest & 1) * BM;
    const int n0 = (rest >> 1) * BN;
    const int kbase = kc * KC;

    // ---- staging: per wave 2 A-chunks + 2 B-chunks of 1 KB (4 gl_lds16/tile)
    const short* asrc[2]; const float* bsrc[2];
    int aofs[2], bofs[2];
#pragma unroll
    for (int u = 0; u < 2; ++u) {
        const int g = w * 2 + u;                         // chunk 0..7
        const int r = lane >> 2;                         // row-in-chunk 0..15
        const int lq = (lane & 3) ^ ((r >> 1) & 3);      // baked swizzle
        asrc[u] = Abf + (size_t)(m0 + g * 16 + r) * FEAT + kbase + lq * 8;
        aofs[u] = g * 512;                               // shorts
        const int kr = g * 4 + (lane >> 4);              // k-row 0..31
        bsrc[u] = T + (size_t)(kbase + kr) * NOUT + n0 + (lane & 15) * 4;
        bofs[u] = g * 256;                               // floats
    }

    // ---- fragment offsets
    int aro[4], bro[2];
#pragma unroll
    for (int mf = 0; mf < 4; ++mf) {
        int row = wm + mf * 16 + l15;
        aro[mf] = row * BK + (((lane >> 4) ^ ((row >> 1) & 3)) * 8);
    }
#pragma unroll
    for (int nf = 0; nf < 2; ++nf)
        bro[nf] = (wn + nf * 16 + l15) * BBP + (lane >> 4) * 8;

    // ---- transpose constants: thread owns col tn (0..63), k-oct th (0..3)
    const int tn = tid & 63, th = tid >> 6;

    f32x4 acc[4][2];
#pragma unroll
    for (int mf = 0; mf < 4; ++mf)
#pragma unroll
        for (int nf = 0; nf < 2; ++nf) acc[mf][nf] = (f32x4){0.f, 0.f, 0.f, 0.f};

#define STAGE(tt, s)                                                          \
    {                                                                         \
        _Pragma("unroll")                                                     \
        for (int u = 0; u < 2; ++u)                                           \
            gl_lds16(asrc[u] + (tt) * BK, &Als[0][0] + (s) * (BM * BK) + aofs[u]); \
        _Pragma("unroll")                                                     \
        for (int u = 0; u < 2; ++u)                                           \
            gl_lds16(bsrc[u] + (size_t)(tt) * BK * NOUT,                      \
                     &Bfs[0][0] + (s) * (BK * BN) + bofs[u]);                 \
    }

#define TRANSPOSE(tt)                                                         \
    {                                                                         \
        const float* bp = &Bfs[0][0] + ((tt) % 3) * (BK * BN);                \
        float v[8];                                                           \
        _Pragma("unroll")                                                     \
        for (int j = 0; j < 8; ++j) v[j] = bp[(th * 8 + j) * BN + tn];        \
        bf16x4 lo = cvt4(v[0], v[1], v[2], v[3]);                             \
        bf16x4 hi = cvt4(v[4], v[5], v[6], v[7]);                             \
        bf16x8 q;                                                             \
        q[0] = lo.x; q[1] = lo.y; q[2] = lo.z; q[3] = lo.w;                   \
        q[4] = hi.x; q[5] = hi.y; q[6] = hi.z; q[7] = hi.w;                   \
        *(bf16x8*)(&Bbf[0][0] + ((tt) & 1) * (BN * BBP) + tn * BBP + th * 8) = q; \
    }

    // ---- prologue
    STAGE(0, 0);
    STAGE(1, 1);
    asm volatile("s_waitcnt vmcnt(4)" ::: "memory");
    __builtin_amdgcn_s_barrier();
    asm volatile("" ::: "memory");
    TRANSPOSE(0);

#pragma unroll
    for (int kt = 0; kt < NSTEP; ++kt) {
        // barrier0: all LDS reads/writes of prev iteration done -> slots reusable
        asm volatile("s_waitcnt lgkmcnt(0)" ::: "memory");
        __builtin_amdgcn_s_barrier();
        asm volatile("" ::: "memory");
        if (kt + 2 < NSTEP) STAGE(kt + 2, (kt + 2) % 3);
        // fragments of tile kt (data stable: nobody writes Als[kt%3]/Bbf[kt&1] now)
        const short* ap = &Als[0][0] + (kt % 3) * (BM * BK);
        const short* bq = &Bbf[0][0] + (kt & 1) * (BN * BBP);
        bf16x8 af[4], bf[2];
#pragma unroll
        for (int mf = 0; mf < 4; ++mf) af[mf] = *(const bf16x8*)(ap + aro[mf]);
#pragma unroll
        for (int nf = 0; nf < 2; ++nf) bf[nf] = *(const bf16x8*)(bq + bro[nf]);
        if (kt + 1 < NSTEP) {
            if (kt + 2 < NSTEP) asm volatile("s_waitcnt vmcnt(4)" ::: "memory");
            else                asm volatile("s_waitcnt vmcnt(0)" ::: "memory");
            __builtin_amdgcn_s_barrier();                 // barrier1: tile kt+1 landed
            asm volatile("" ::: "memory");
            TRANSPOSE(kt + 1);                            // -> Bbf[(kt+1)&1]
        }
        __builtin_amdgcn_s_setprio(1);
#pragma unroll
        for (int mf = 0; mf < 4; ++mf)
#pragma unroll
            for (int nf = 0; nf < 2; ++nf)
                acc[mf][nf] = __builtin_amdgcn_mfma_f32_16x16x32_bf16(
                    af[mf], bf[nf], acc[mf][nf], 0, 0, 0);
        __builtin_amdgcn_s_setprio(0);
    }
#undef STAGE
#undef TRANSPOSE

    // epilogue: C/D layout col = l&15, row = (l>>4)*4 + r  [m89-verified]
    short* Mp = Mt + (size_t)kc * NOUT * NS;
    const int r0 = (lane >> 4) * 4;
#pragma unroll
    for (int mf = 0; mf < 4; ++mf)
#pragma unroll
        for (int nf = 0; nf < 2; ++nf) {
            int col = n0 + wn + nf * 16 + l15;
            int row = m0 + wm + mf * 16 + r0;
            *(bf16x4*)&Mp[(size_t)col * NS + row] =
                cvt4(acc[mf][nf].x, acc[mf][nf].y, acc[mf][nf].z, acc[mf][nf].w);
        }
}

// ------------------------------------------------------- DMA ablation probe -
// Same staging skeleton (gl_lds16, ring-3, counted vmcnt, 2 barriers/step) but
// NO transpose / frags / MFMA. Streams the block's T+A slabs PASSES times.
// Purpose: measure the skeleton's achievable streaming rate in isolation;
// sized to exceed 40 us so it surfaces in rocprof top-5 with its own counters.
__global__ __launch_bounds__(256, 2) void mbd_probe_dma_kernel(const short* __restrict__ Abf,
                                                               const float* __restrict__ T,
                                                               float* __restrict__ junk) {
    __shared__ __align__(16) short Als[3][BM * BK];
    __shared__ __align__(16) float Bfs[3][BK * BN];

    const int tid = threadIdx.x, lane = tid & 63, w = tid >> 6;
    const int bx = blockIdx.x;
    const int kc = bx & 15;
    const int rest = bx >> 4;
    const int m0 = (rest & 1) * BM;
    const int n0 = (rest >> 1) * BN;
    const int kbase = kc * KC;

    const short* asrc[2]; const float* bsrc[2];
    int aofs[2], bofs[2];
#pragma unroll
    for (int u = 0; u < 2; ++u) {
        const int g = w * 2 + u;
        const int r = lane >> 2;
        const int lq = (lane & 3) ^ ((r >> 1) & 3);
        asrc[u] = Abf + (size_t)(m0 + g * 16 + r) * FEAT + kbase + lq * 8;
        aofs[u] = g * 512;
        const int kr = g * 4 + (lane >> 4);
        bsrc[u] = T + (size_t)(kbase + kr) * NOUT + n0 + (lane & 15) * 4;
        bofs[u] = g * 256;
    }

#define PSTAGE(st, s)                                                         \
    {                                                                         \
        const int tt = (st) & (NSTEP - 1);                                    \
        _Pragma("unroll")                                                     \
        for (int u = 0; u < 2; ++u)                                           \
            gl_lds16(asrc[u] + tt * BK, &Als[0][0] + (s) * (BM * BK) + aofs[u]); \
        _Pragma("unroll")                                                     \
        for (int u = 0; u < 2; ++u)                                           \
            gl_lds16(bsrc[u] + (size_t)tt * BK * NOUT,                        \
                     &Bfs[0][0] + (s) * (BK * BN) + bofs[u]);                 \
    }

    const int NT = PASSES * NSTEP;
    PSTAGE(0, 0);
    PSTAGE(1, 1);
    asm volatile("s_waitcnt vmcnt(4)" ::: "memory");
    __builtin_amdgcn_s_barrier();
    asm volatile("" ::: "memory");

    for (int st = 0; st < NT; ++st) {
        __builtin_amdgcn_s_barrier();                     // barrier0 analog
        asm volatile("" ::: "memory");
        if (st + 2 < NT) PSTAGE(st + 2, (st + 2) % 3);
        if (st + 1 < NT) {
            if (st + 2 < NT) asm volatile("s_waitcnt vmcnt(4)" ::: "memory");
            else             asm volatile("s_waitcnt vmcnt(0)" ::: "memory");
            __builtin_amdgcn_s_barrier();                 // barrier1 analog
            asm volatile("" ::: "memory");
        }
    }
#undef PSTAGE

    // keep-alive (cannot be proven false by the compiler; practically never taken)
    float v = Bfs[0][tid] + (float)Als[0][tid];
    if (v == 1.2345e-38f) junk[tid] = v;
}

// ---------------------------------------------------------------- pairwise --
__global__ __launch_bounds__(256) void mbd_pair_kernel(const short* __restrict__ Mt,
                                                       float* __restrict__ out) {
    const int b = blockIdx.x >> 1, jh = blockIdx.x & 1;
    const int t = threadIdx.x;
    __shared__ float ldsT[CD][NS];
    __shared__ float rows[NS][20];

#pragma unroll
    for (int u4 = 0; u4 < 4; ++u4) {
        int u = t + u4 * 256;
        int c = u >> 6, r4 = (u & 63) * 4;
        f32x4 v = (f32x4){0.f, 0.f, 0.f, 0.f};
#pragma unroll
        for (int p = 0; p < KSPLIT; ++p)
            v += bf4_to_f32(*(const bf16x4*)(Mt +
                     ((size_t)p * NOUT + (size_t)b * CD + c) * NS + r4));
        *(f32x4*)&ldsT[c][r4] = v;
    }
    __syncthreads();

    float my[16];
#pragma unroll
    for (int c = 0; c < 16; ++c) my[c] = ldsT[c][t];
#pragma unroll
    for (int c = 0; c < 16; ++c) rows[t][c] = my[c];
    __syncthreads();

    float o0 = 0.f, o1 = 0.f;
    const int jbase = jh * 128;
    for (int jj = 0; jj < 128; jj += 2) {
#pragma unroll
        for (int s = 0; s < 2; ++s) {
            const float* rp = &rows[jbase + jj + s][0];
            float d0 = 0.f, d1 = 0.f, d2 = 0.f, d3 = 0.f;
#pragma unroll
            for (int q = 0; q < 4; ++q) {
                f32x4 r = *(const f32x4*)(rp + q * 4);
                d0 += fabsf(my[q * 4 + 0] - r.x);
                d1 += fabsf(my[q * 4 + 1] - r.y);
                d2 += fabsf(my[q * 4 + 2] - r.z);
                d3 += fabsf(my[q * 4 + 3] - r.w);
            }
            float d = (d0 + d1) + (d2 + d3);
            if (s == 0) o0 += __expf(-d); else o1 += __expf(-d);
        }
    }
    atomicAdd(&out[(size_t)t * OUTW + FEAT + b], o0 + o1);
}

// ---------------------------------------------------------------- launch ----
extern "C" void kernel_launch(void* const* d_in, const int* in_sizes, int n_in,
                              void* d_out, int out_size, void* d_ws, size_t ws_size,
                              hipStream_t stream) {
    const float* inp = (const float*)d_in[0];
    const float* T   = (const float*)d_in[1];
    float* out = (float*)d_out;

    short* Abf = (short*)d_ws;                       // 4 MiB
    short* Mt  = Abf + (size_t)NS * FEAT;            // 16 MiB
    float* junk = (float*)((char*)d_ws + (48u << 20));

    mbd_copy_kernel<<<dim3(9, 256), 256, 0, stream>>>(inp, out, Abf);
    mbd_gemm_kernel<<<1024, 256, 0, stream>>>(Abf, T, Mt);
    mbd_pair_kernel<<<BD * 2, 256, 0, stream>>>(Mt, out);
    if (ws_size >= (64u << 20))
        mbd_probe_dma_kernel<<<1024, 256, 0, stream>>>(Abf, T, junk);
}

// Round 9
// 61.823 us; speedup vs baseline: 2.4025x; 2.4025x over previous
//
#include <hip/hip_runtime.h>
#include <hip/hip_bf16.h>

#define NS     256
#define FEAT   8192
#define BD     128
#define CD     16
#define NOUT   2048
#define OUTW   8320              // FEAT + BD
#define KSPLIT 16
#define KC     (FEAT / KSPLIT)   // 512
#define BK     64
#define NSTEP  (KC / BK)         // 8
#define BM     256
#define BN     64

typedef float f32x4 __attribute__((ext_vector_type(4)));
typedef short bf16x8 __attribute__((ext_vector_type(8)));
typedef short bf16x4 __attribute__((ext_vector_type(4)));

typedef unsigned int u32;
typedef __attribute__((address_space(3))) u32 lds_u32;
typedef const __attribute__((address_space(1))) u32 gbl_u32;

__device__ __forceinline__ void gl_lds16(const void* g, void* l) {
    __builtin_amdgcn_global_load_lds((gbl_u32*)g, (lds_u32*)l, 16, 0, 0);
}

__device__ __forceinline__ bf16x4 cvt4(float a, float b, float c, float d) {
    union { __hip_bfloat162 h[2]; bf16x4 s; } u;
    u.h[0] = __float22bfloat162_rn(float2{a, b});
    u.h[1] = __float22bfloat162_rn(float2{c, d});
    return u.s;
}

__device__ __forceinline__ f32x4 bf4_to_f32(bf16x4 s) {
    f32x4 r;
    r.x = __uint_as_float(((u32)(unsigned short)s.x) << 16);
    r.y = __uint_as_float(((u32)(unsigned short)s.y) << 16);
    r.z = __uint_as_float(((u32)(unsigned short)s.z) << 16);
    r.w = __uint_as_float(((u32)(unsigned short)s.w) << 16);
    return r;
}

// -------------------------------- copy inp -> out, zero o-cols, produce Abf -
__global__ __launch_bounds__(256) void mbd_copy_kernel(const float* __restrict__ in,
                                                       float* __restrict__ out,
                                                       short* __restrict__ Abf) {
    int row = blockIdx.y;
    int c4  = blockIdx.x * 256 + threadIdx.x;
    if (c4 < 2048) {
        f32x4 v = *(const f32x4*)(in + (size_t)row * FEAT + c4 * 4);
        *(f32x4*)(out + (size_t)row * OUTW + c4 * 4) = v;
        *(bf16x4*)(Abf + (size_t)row * FEAT + c4 * 4) = cvt4(v.x, v.y, v.z, v.w);
    } else if (c4 < 2080) {
        *(f32x4*)(out + (size_t)row * OUTW + c4 * 4) = (f32x4){0.f, 0.f, 0.f, 0.f};
    }
}

// ---------------------------------------------------------------- GEMM ------
// Mt_part[kc][col][row] (bf16) = (Abf[:, kc-slice] @ T[kc-slice, :])^T.
// B (T) is NOT staged in LDS: MFMA B-fragments load straight from global
// (each dword instruction = 4 k-rows x 64B, 100% line use; every T element
// read by exactly one block). Compiler manages all vmcnt. A staged in LDS
// (dbuf, gl_lds16, 8-slot XOR swizzle baked into the global source address);
// ONE __syncthreads per K-step is the only synchronization.
// 512 thr (8 waves, 4m x 2n; wave tile 64x32), grid 512 -> 2 blocks/CU.
__global__ __launch_bounds__(512, 4) void mbd_gemm_kernel(const short* __restrict__ Abf,
                                                          const float* __restrict__ T,
                                                          short* __restrict__ Mt) {
    __shared__ __align__(16) short Als[2][BM * BK];   // 2 x 32 KB

    const int tid = threadIdx.x, lane = tid & 63, l15 = lane & 15, w = tid >> 6;
    const int q = lane >> 4;                 // lane quarter 0..3
    const int wm = (w & 3) * 64, wn = (w >> 2) * 32;

    const int kc = blockIdx.x & 15;          // bx%8==kc%8 -> A slabs L2-resident/XCD
    const int n0 = (blockIdx.x >> 4) * BN;
    const int kbase = kc * KC;

    // ---- A staging: 32 chunks of 1 KB (8 rows x 128 B); wave w owns 4.
    // LDS[row][slot s] (16B slots) holds logical slot sl = s ^ (row&7);
    // source address pre-applies the swizzle (gl_lds16 dest = base + lane*16).
    const short* asrc[4];
    int aofs[4];
#pragma unroll
    for (int u = 0; u < 4; ++u) {
        const int g  = w * 4 + u;            // chunk 0..31
        const int r7 = lane >> 3;            // row-in-chunk 0..7
        const int sl = (lane & 7) ^ r7;      // logical slot this lane fetches
        const int koff = (sl >> 2) * 32 + (sl & 3) * 8;
        asrc[u] = Abf + (size_t)(g * 8 + r7) * FEAT + kbase + koff;
        aofs[u] = g * 512;                   // shorts
    }

    // ---- A fragment offsets (shorts): row*64 + ((h*4+q)^(row&7))*8
    int aro[2][4];
#pragma unroll
    for (int h = 0; h < 2; ++h)
#pragma unroll
        for (int mf = 0; mf < 4; ++mf) {
            int row = wm + mf * 16 + l15;
            aro[h][mf] = row * BK + (((h * 4 + q) ^ (row & 7)) * 8);
        }

    // ---- B base: lane column + lane-quarter k-offset
    const float* bbase = T + ((size_t)kbase + q * 8) * NOUT + n0 + wn + l15;

    f32x4 acc[4][2];
#pragma unroll
    for (int mf = 0; mf < 4; ++mf)
#pragma unroll
        for (int nf = 0; nf < 2; ++nf) acc[mf][nf] = (f32x4){0.f, 0.f, 0.f, 0.f};

    // prologue: stage A tile 0
#pragma unroll
    for (int u = 0; u < 4; ++u) gl_lds16(asrc[u], &Als[0][aofs[u]]);
    __syncthreads();

    for (int kt = 0; kt < NSTEP; ++kt) {
        const int cur = kt & 1;
        // stage A tile kt+1 into the other buffer (fire-and-forget DMA)
        if (kt + 1 < NSTEP) {
#pragma unroll
            for (int u = 0; u < 4; ++u)
                gl_lds16(asrc[u] + (kt + 1) * BK, &Als[cur ^ 1][aofs[u]]);
        }
        // B fragments straight from global (compiler-pipelined)
        float br[2][2][8];
        const float* bp = bbase + (size_t)kt * BK * NOUT;
#pragma unroll
        for (int h = 0; h < 2; ++h)
#pragma unroll
            for (int nf = 0; nf < 2; ++nf)
#pragma unroll
                for (int j = 0; j < 8; ++j)
                    br[h][nf][j] = bp[(size_t)(h * 32 + j) * NOUT + nf * 16];
        // A fragments from LDS
        bf16x8 af[2][4];
#pragma unroll
        for (int h = 0; h < 2; ++h)
#pragma unroll
            for (int mf = 0; mf < 4; ++mf)
                af[h][mf] = *(const bf16x8*)&Als[cur][aro[h][mf]];
        // convert B, MFMA
        __builtin_amdgcn_s_setprio(1);
#pragma unroll
        for (int h = 0; h < 2; ++h) {
            bf16x8 bf[2];
#pragma unroll
            for (int nf = 0; nf < 2; ++nf) {
                bf16x4 lo = cvt4(br[h][nf][0], br[h][nf][1], br[h][nf][2], br[h][nf][3]);
                bf16x4 hi = cvt4(br[h][nf][4], br[h][nf][5], br[h][nf][6], br[h][nf][7]);
                bf16x8 t;
                t[0] = lo.x; t[1] = lo.y; t[2] = lo.z; t[3] = lo.w;
                t[4] = hi.x; t[5] = hi.y; t[6] = hi.z; t[7] = hi.w;
                bf[nf] = t;
            }
#pragma unroll
            for (int mf = 0; mf < 4; ++mf)
#pragma unroll
                for (int nf = 0; nf < 2; ++nf)
                    acc[mf][nf] = __builtin_amdgcn_mfma_f32_16x16x32_bf16(
                        af[h][mf], bf[nf], acc[mf][nf], 0, 0, 0);
        }
        __builtin_amdgcn_s_setprio(0);
        if (kt + 1 < NSTEP) __syncthreads();   // drains DMA; protects dbuf swap
    }

    // epilogue: C/D layout col = l&15, row = (l>>4)*4 + r  [m89-verified]
    short* Mp = Mt + (size_t)kc * NOUT * NS;
    const int r0 = q * 4;
#pragma unroll
    for (int mf = 0; mf < 4; ++mf)
#pragma unroll
        for (int nf = 0; nf < 2; ++nf) {
            int col = n0 + wn + nf * 16 + l15;
            int row = wm + mf * 16 + r0;
            *(bf16x4*)&Mp[(size_t)col * NS + row] =
                cvt4(acc[mf][nf].x, acc[mf][nf].y, acc[mf][nf].z, acc[mf][nf].w);
        }
}

// ---------------------------------------------------------------- pairwise --
// block (b, jhalf): o_part[i,b] = sum_{j in half} exp(-sum_c |M[i,c]-M[j,c]|)
__global__ __launch_bounds__(256) void mbd_pair_kernel(const short* __restrict__ Mt,
                                                       float* __restrict__ out) {
    const int b = blockIdx.x >> 1, jh = blockIdx.x & 1;
    const int t = threadIdx.x;
    __shared__ float ldsT[CD][NS];
    __shared__ float rows[NS][20];

#pragma unroll
    for (int u4 = 0; u4 < 4; ++u4) {
        int u = t + u4 * 256;
        int c = u >> 6, r4 = (u & 63) * 4;
        f32x4 v = (f32x4){0.f, 0.f, 0.f, 0.f};
#pragma unroll
        for (int p = 0; p < KSPLIT; ++p)
            v += bf4_to_f32(*(const bf16x4*)(Mt +
                     ((size_t)p * NOUT + (size_t)b * CD + c) * NS + r4));
        *(f32x4*)&ldsT[c][r4] = v;
    }
    __syncthreads();

    float my[16];
#pragma unroll
    for (int c = 0; c < 16; ++c) my[c] = ldsT[c][t];
#pragma unroll
    for (int c = 0; c < 16; ++c) rows[t][c] = my[c];
    __syncthreads();

    float o0 = 0.f, o1 = 0.f;
    const int jbase = jh * 128;
    for (int jj = 0; jj < 128; jj += 2) {
#pragma unroll
        for (int s = 0; s < 2; ++s) {
            const float* rp = &rows[jbase + jj + s][0];
            float d0 = 0.f, d1 = 0.f, d2 = 0.f, d3 = 0.f;
#pragma unroll
            for (int qq = 0; qq < 4; ++qq) {
                f32x4 r = *(const f32x4*)(rp + qq * 4);
                d0 += fabsf(my[qq * 4 + 0] - r.x);
                d1 += fabsf(my[qq * 4 + 1] - r.y);
                d2 += fabsf(my[qq * 4 + 2] - r.z);
                d3 += fabsf(my[qq * 4 + 3] - r.w);
            }
            float d = (d0 + d1) + (d2 + d3);
            if (s == 0) o0 += __expf(-d); else o1 += __expf(-d);
        }
    }
    // exactly two addends per address -> f32 add commutative -> deterministic
    atomicAdd(&out[(size_t)t * OUTW + FEAT + b], o0 + o1);
}

// ---------------------------------------------------------------- launch ----
extern "C" void kernel_launch(void* const* d_in, const int* in_sizes, int n_in,
                              void* d_out, int out_size, void* d_ws, size_t ws_size,
                              hipStream_t stream) {
    const float* inp = (const float*)d_in[0];
    const float* T   = (const float*)d_in[1];
    float* out = (float*)d_out;

    short* Abf = (short*)d_ws;                       // 4 MiB
    short* Mt  = Abf + (size_t)NS * FEAT;            // 16 MiB

    mbd_copy_kernel<<<dim3(9, 256), 256, 0, stream>>>(inp, out, Abf);
    mbd_gemm_kernel<<<512, 512, 0, stream>>>(Abf, T, Mt);
    mbd_pair_kernel<<<BD * 2, 256, 0, stream>>>(Mt, out);
}